// Round 2
// baseline (2781.996 us; speedup 1.0000x reference)
//
#include <hip/hip_runtime.h>
#include <cstdint>
#include <cstddef>

// GRUCore B=256 T=128 D=1024 H=1024 — Round 2: resubmit of round-1 bring-up
// (round 1 died in the container/broker layer with no kernel verdict).
// prep -> gi GEMM (bf16 MFMA, 128x128 tile, global_load_lds w=16)
//      -> 128 step kernels (gate-interleaved W, mask folded by linearity)
//      -> fused LayerNorm + residual.

constexpr int kB = 256, kT = 128, kD = 1024, kH = 1024, kG = 3072;

typedef unsigned short u16;
typedef unsigned int u32;
typedef __attribute__((ext_vector_type(4))) float f32x4;
typedef __attribute__((ext_vector_type(8))) short s16x8;
typedef __attribute__((ext_vector_type(8))) u16 u16x8;
typedef __attribute__((ext_vector_type(4))) u16 u16x4;

__device__ __forceinline__ u16 f2bf(float f) {
  u32 u = __builtin_bit_cast(u32, f);
  u += 0x7fffu + ((u >> 16) & 1u);
  return (u16)(u >> 16);
}
__device__ __forceinline__ float bf2f(u16 s) {
  return __builtin_bit_cast(float, (u32)s << 16);
}
__device__ __forceinline__ void glds16(const void* g, void* l) {
  __builtin_amdgcn_global_load_lds(
      (const __attribute__((address_space(1))) u32*)g,
      (__attribute__((address_space(3))) u32*)l, 16, 0, 0);
}
__device__ __forceinline__ float sigm(float x) { return 1.f / (1.f + __expf(-x)); }
__device__ __forceinline__ float ftanh(float x) {
  float e = __expf(2.f * x);
  return 1.f - 2.f / (e + 1.f);
}

// ---------------- prep kernels ----------------

__global__ __launch_bounds__(256) void cvt_bf16_k(const float* __restrict__ src, u16* __restrict__ dst) {
  size_t i = ((size_t)blockIdx.x * 256 + threadIdx.x) * 8;
  float4 a = *(const float4*)(src + i);
  float4 b2 = *(const float4*)(src + i + 4);
  u16x8 o;
  o[0] = f2bf(a.x); o[1] = f2bf(a.y); o[2] = f2bf(a.z); o[3] = f2bf(a.w);
  o[4] = f2bf(b2.x); o[5] = f2bf(b2.y); o[6] = f2bf(b2.z); o[7] = f2bf(b2.w);
  *(u16x8*)(dst + i) = o;
}

__global__ __launch_bounds__(256) void cvt_hx_k(const float* __restrict__ hx, u16* __restrict__ hb,
                                                float* __restrict__ hf) {
  size_t i = ((size_t)blockIdx.x * 256 + threadIdx.x) * 8;
  float4 a = *(const float4*)(hx + i);
  float4 b2 = *(const float4*)(hx + i + 4);
  u16x8 o;
  o[0] = f2bf(a.x); o[1] = f2bf(a.y); o[2] = f2bf(a.z); o[3] = f2bf(a.w);
  o[4] = f2bf(b2.x); o[5] = f2bf(b2.y); o[6] = f2bf(b2.z); o[7] = f2bf(b2.w);
  *(u16x8*)(hb + i) = o;
  *(float4*)(hf + i) = a;
  *(float4*)(hf + i + 4) = b2;
}

// gate-interleave permutation: out row n' = j*48+s (s: 0-15 r, 16-31 z, 32-47 n)
//   <- orig row (s>>4)*1024 + j*16 + (s&15)
__global__ __launch_bounds__(256) void perm_w_k(const float* __restrict__ Wih, const float* __restrict__ Whh,
                                                const float* __restrict__ bih, const float* __restrict__ bhh,
                                                u16* __restrict__ Wihp, u16* __restrict__ Whhp,
                                                float* __restrict__ bihp, float* __restrict__ bhhp) {
  int np = blockIdx.x, tid = threadIdx.x;
  int j = np / 48, s2 = np - j * 48;
  int orig = (s2 >> 4) * kH + j * 16 + (s2 & 15);
  float4 a = ((const float4*)(Wih + (size_t)orig * kD))[tid];
  float4 b2 = ((const float4*)(Whh + (size_t)orig * kH))[tid];
  u16x4 oa, ob;
  oa[0] = f2bf(a.x); oa[1] = f2bf(a.y); oa[2] = f2bf(a.z); oa[3] = f2bf(a.w);
  ob[0] = f2bf(b2.x); ob[1] = f2bf(b2.y); ob[2] = f2bf(b2.z); ob[3] = f2bf(b2.w);
  *(u16x4*)(Wihp + (size_t)np * kD + tid * 4) = oa;
  *(u16x4*)(Whhp + (size_t)np * kH + tid * 4) = ob;
  if (tid == 0) { bihp[np] = bih[orig]; bhhp[np] = bhh[orig]; }
}

// ---------------- gi GEMM: m97-style 128x128 bf16 MFMA ----------------
// C[m][n] = sum_k A[m][k]*Bw[n][k];  m=(b*128+t); out gi[t][b][n] bf16 (+bias)

__global__ __launch_bounds__(256) void gi_gemm_k(const u16* __restrict__ A, const u16* __restrict__ Bw,
                                                 const float* __restrict__ bih, u16* __restrict__ gi) {
  __shared__ u16 As[128 * 32];
  __shared__ u16 Bs[128 * 32];
  int bid = blockIdx.x;
  int b2 = (bid & 7) * 768 + (bid >> 3);  // XCD swizzle (6144 % 8 == 0, bijective)
  int m0 = (b2 / 24) * 128, n0 = (b2 % 24) * 128;
  int tid = threadIdx.x, w = tid >> 6, lane = tid & 63;
  int wm = (w >> 1) * 64, wn = (w & 1) * 64;
  f32x4 acc[4][4] = {};
  for (int kt = 0; kt < 32; ++kt) {
    int k0 = kt * 32;
#pragma unroll
    for (int p = 0; p < 2; ++p) {
      int c = w * 2 + p;
      int e = c * 512 + lane * 8;
      int row = e >> 5, kk = e & 31;
      glds16(A + (size_t)(m0 + row) * kD + k0 + kk, (char*)As + c * 1024);
      glds16(Bw + (size_t)(n0 + row) * kD + k0 + kk, (char*)Bs + c * 1024);
    }
    __syncthreads();
    int fr = lane & 15, fo = (lane >> 4) * 16;
    s16x8 af[4], bfr[4];
#pragma unroll
    for (int mi = 0; mi < 4; ++mi)
      af[mi] = *(const s16x8*)((const char*)As + (wm + mi * 16 + fr) * 64 + fo);
#pragma unroll
    for (int ni = 0; ni < 4; ++ni)
      bfr[ni] = *(const s16x8*)((const char*)Bs + (wn + ni * 16 + fr) * 64 + fo);
#pragma unroll
    for (int mi = 0; mi < 4; ++mi)
#pragma unroll
      for (int ni = 0; ni < 4; ++ni)
        acc[mi][ni] = __builtin_amdgcn_mfma_f32_16x16x32_bf16(af[mi], bfr[ni], acc[mi][ni], 0, 0, 0);
    __syncthreads();
  }
  int fr = lane & 15, rb = (lane >> 4) * 4;
#pragma unroll
  for (int ni = 0; ni < 4; ++ni) {
    int n = n0 + wn + ni * 16 + fr;
    float bv = bih[n];
#pragma unroll
    for (int mi = 0; mi < 4; ++mi) {
#pragma unroll
      for (int i2 = 0; i2 < 4; ++i2) {
        int m = m0 + wm + mi * 16 + rb + i2;
        int b = m >> 7, t = m & 127;
        gi[((size_t)t * kB + b) * kG + n] = f2bf(acc[mi][ni][i2] + bv);
      }
    }
  }
}

// ---------------- one recurrence step ----------------
// grid (64 Ng, 4 Mg), 256 thr. Block: batches Mg*64..+64, h-cols Ng*16..+16.
// gh = h_bf16 @ Whh_p^T (48 rows = r/z/n x16), mask folded in epilogue.

__global__ __launch_bounds__(256) void gru_step_k(
    const u16* __restrict__ Whh, const u16* __restrict__ gi, const float* __restrict__ bhh,
    const int* __restrict__ is_init, const u16* __restrict__ hb_prev, u16* __restrict__ hb_next,
    const float* __restrict__ hf_prev, float* __restrict__ hf_next,
    float* __restrict__ Hs, int t) {
  __shared__ u16 Wc[48 * 128];
  __shared__ u16 Hc[64 * 128];
  int Ng = blockIdx.x, Mg = blockIdx.y;
  int tid = threadIdx.x, w = tid >> 6, lane = tid & 63;
  f32x4 acc[3] = {};
  const u16* Wbase = Whh + (size_t)(48 * Ng) * kH;
  const u16* Hbase = hb_prev + (size_t)(Mg * 64) * kH;
  for (int kc = 0; kc < 8; ++kc) {
    int k0 = kc * 128;
#pragma unroll
    for (int i2 = 0; i2 < 3; ++i2) {  // W stripe: 48x128 bf16 = 12 KB
      int c = w * 3 + i2;
      int e = c * 512 + lane * 8;
      glds16(Wbase + (size_t)(e >> 7) * kH + k0 + (e & 127), (char*)Wc + c * 1024);
    }
#pragma unroll
    for (int i2 = 0; i2 < 4; ++i2) {  // h tile: 64x128 bf16 = 16 KB
      int c = w * 4 + i2;
      int e = c * 512 + lane * 8;
      glds16(Hbase + (size_t)(e >> 7) * kH + k0 + (e & 127), (char*)Hc + c * 1024);
    }
    __syncthreads();
    int fr = lane & 15, fo = (lane >> 4) * 16;
#pragma unroll
    for (int ks = 0; ks < 4; ++ks) {
      s16x8 hfr = *(const s16x8*)((const char*)Hc + (w * 16 + fr) * 256 + ks * 64 + fo);
#pragma unroll
      for (int g = 0; g < 3; ++g) {
        s16x8 wfr = *(const s16x8*)((const char*)Wc + (g * 16 + fr) * 256 + ks * 64 + fo);
        acc[g] = __builtin_amdgcn_mfma_f32_16x16x32_bf16(hfr, wfr, acc[g], 0, 0, 0);
      }
    }
    __syncthreads();
  }
  int fr = lane & 15;
  int hcol = Ng * 16 + fr;
  float br = bhh[48 * Ng + fr], bz = bhh[48 * Ng + 16 + fr], bn = bhh[48 * Ng + 32 + fr];
#pragma unroll
  for (int i2 = 0; i2 < 4; ++i2) {
    int b = Mg * 64 + w * 16 + (lane >> 4) * 4 + i2;
    float m = is_init[b * kT + t] ? 0.f : 1.f;
    size_t gb = ((size_t)t * kB + b) * kG + 48 * Ng;
    float gir = bf2f(gi[gb + fr]);
    float giz = bf2f(gi[gb + 16 + fr]);
    float gin = bf2f(gi[gb + 32 + fr]);
    float r = sigm(gir + m * acc[0][i2] + br);
    float z = sigm(giz + m * acc[1][i2] + bz);
    float n = ftanh(gin + r * (m * acc[2][i2] + bn));
    float hp = m * hf_prev[(size_t)b * kH + hcol];
    float hv = (1.f - z) * n + z * hp;
    hb_next[(size_t)b * kH + hcol] = f2bf(hv);
    hf_next[(size_t)b * kH + hcol] = hv;
    Hs[((size_t)b * kT + t) * kH + hcol] = hv;
  }
}

// ---------------- LayerNorm + gated residual ----------------

__global__ __launch_bounds__(256) void ln_res_k(const float* __restrict__ Hs, const float* __restrict__ x,
                                                const float* __restrict__ g, const float* __restrict__ be,
                                                const float* __restrict__ rg, float* __restrict__ Y) {
  int row = blockIdx.x;
  int tid = threadIdx.x;
  size_t base = (size_t)row * kH;
  float4 v = ((const float4*)(Hs + base))[tid];
  float s = v.x + v.y + v.z + v.w;
  float ss = v.x * v.x + v.y * v.y + v.z * v.z + v.w * v.w;
#pragma unroll
  for (int off = 32; off > 0; off >>= 1) {
    s += __shfl_down(s, off);
    ss += __shfl_down(ss, off);
  }
  __shared__ float red[8];
  int w = tid >> 6;
  if ((tid & 63) == 0) { red[w] = s; red[4 + w] = ss; }
  __syncthreads();
  s = red[0] + red[1] + red[2] + red[3];
  ss = red[4] + red[5] + red[6] + red[7];
  float mu = s * (1.f / kH);
  float rs = rsqrtf(ss * (1.f / kH) - mu * mu + 1e-5f);
  float4 xv = ((const float4*)(x + base))[tid];
  float4 gv = ((const float4*)g)[tid];
  float4 bv = ((const float4*)be)[tid];
  float4 rv = ((const float4*)rg)[tid];
  float4 o;
  o.x = (v.x - mu) * rs * gv.x + bv.x + xv.x * sigm(rv.x);
  o.y = (v.y - mu) * rs * gv.y + bv.y + xv.y * sigm(rv.y);
  o.z = (v.z - mu) * rs * gv.z + bv.z + xv.z * sigm(rv.z);
  o.w = (v.w - mu) * rs * gv.w + bv.w + xv.w * sigm(rv.w);
  ((float4*)(Y + base))[tid] = o;
}

// ---------------- launch ----------------

extern "C" void kernel_launch(void* const* d_in, const int* in_sizes, int n_in,
                              void* d_out, int out_size, void* d_ws, size_t ws_size,
                              hipStream_t stream) {
  const float* x = (const float*)d_in[0];
  const float* hx = (const float*)d_in[1];
  const int* is_init = (const int*)d_in[2];
  const float* Wih = (const float*)d_in[3];
  const float* Whh = (const float*)d_in[4];
  const float* bih = (const float*)d_in[5];
  const float* bhh = (const float*)d_in[6];
  const float* lng = (const float*)d_in[7];
  const float* lnb = (const float*)d_in[8];
  const float* rg = (const float*)d_in[9];
  float* Y = (float*)d_out;
  float* Hs = Y + (size_t)kB * kT * kH;

  char* ws = (char*)d_ws;
  u16* xb = (u16*)(ws + 0);                 //  67,108,864 B
  u16* Wihp = (u16*)(ws + 67108864);        //   6,291,456
  u16* Whhp = (u16*)(ws + 73400320);        //   6,291,456
  float* bihp = (float*)(ws + 79691776);    //      12,288
  float* bhhp = (float*)(ws + 79704064);    //      12,288
  u16* hb0 = (u16*)(ws + 79716352);         //     524,288
  u16* hb1 = (u16*)(ws + 80240640);         //     524,288
  float* hf0 = (float*)(ws + 80764928);     //   1,048,576
  float* hf1 = (float*)(ws + 81813504);     //   1,048,576
  u16* gi = (u16*)(ws + 82862080);          // 201,326,592  -> total 284,188,672
  if (ws_size < 284188672ull) return;       // fail loudly rather than corrupt

  cvt_bf16_k<<<16384, 256, 0, stream>>>(x, xb);
  perm_w_k<<<3072, 256, 0, stream>>>(Wih, Whh, bih, bhh, Wihp, Whhp, bihp, bhhp);
  cvt_hx_k<<<128, 256, 0, stream>>>(hx, hb0, hf0);
  gi_gemm_k<<<6144, 256, 0, stream>>>(xb, Wihp, bihp, gi);
  for (int t = 0; t < kT; ++t) {
    const u16* hbp = (t & 1) ? hb1 : hb0;
    u16* hbn = (t & 1) ? hb0 : hb1;
    const float* hfp = (t & 1) ? hf1 : hf0;
    float* hfn = (t & 1) ? hf0 : hf1;
    gru_step_k<<<dim3(64, 4), 256, 0, stream>>>(Whhp, gi, bhhp, is_init, hbp, hbn, hfp, hfn, Hs, t);
  }
  ln_res_k<<<32768, 256, 0, stream>>>(Hs, x, lng, lnb, rg, Y);
}